// Round 4
// baseline (399.466 us; speedup 1.0000x reference)
//
#include <hip/hip_runtime.h>
#include <hip/hip_bf16.h>

// Problem constants
#define BB 16
#define NN 1024
#define CC 768
#define HH 12
#define DH 64
#define NSC 196
#define N1 1220              // NN + NSC
#define MPAD 19584           // 153*128, padded row count of xt
#define M_QKV (BB * N1)      // 19520 (valid rows)
#define N_QKV (3 * CC)       // 2304
#define M_PROJ (BB * NN)     // 16384
#define KP 1224              // VT padded key count; 192*64*KP*2 B == MPAD*CC*2 B exactly

typedef __attribute__((ext_vector_type(8))) short short8;   // 8 bf16 = 4 VGPRs
typedef __attribute__((ext_vector_type(4))) float f32x4;

#define SC2F 0.18033688011f   // 0.125 * log2(e): folded into Q, softmax in exp2 domain

__device__ __forceinline__ void load_lds16(const void* g, void* l) {
    __builtin_amdgcn_global_load_lds(
        (__attribute__((address_space(1))) void*)(g),
        (__attribute__((address_space(3))) void*)(l),
        16, 0, 0);
}

// ---------------------------------------------------------------------------
// Cast kernels (one-time): build bf16 xt (concat + zero-pad) and transposed
// bf16 weights so GEMM B operand is row-major [n][k].
// ---------------------------------------------------------------------------
__global__ __launch_bounds__(256) void cast_xt_kernel(
    const float* __restrict__ x, const float* __restrict__ sct,
    __hip_bfloat16* __restrict__ xt)
{
    const int e   = blockIdx.x * 256 + threadIdx.x;   // MPAD*96 threads
    const int row = e / 96;
    const int c8  = (e - row * 96) * 8;
    union { short8 s; __hip_bfloat16 h[8]; } u;
    if (row < M_QKV) {
        const int b  = row / N1;
        const int rr = row - b * N1;
        const float* src = (rr < NN)
            ? x   + ((size_t)b * NN + rr) * CC + c8
            : sct + (size_t)(rr - NN) * CC + c8;
        const float4 v0 = *(const float4*)src;
        const float4 v1 = *(const float4*)(src + 4);
        u.h[0] = __float2bfloat16(v0.x); u.h[1] = __float2bfloat16(v0.y);
        u.h[2] = __float2bfloat16(v0.z); u.h[3] = __float2bfloat16(v0.w);
        u.h[4] = __float2bfloat16(v1.x); u.h[5] = __float2bfloat16(v1.y);
        u.h[6] = __float2bfloat16(v1.z); u.h[7] = __float2bfloat16(v1.w);
    } else {
#pragma unroll
        for (int j = 0; j < 8; ++j) u.h[j] = __float2bfloat16(0.f);
    }
    *(short8*)(xt + (size_t)row * CC + c8) = u.s;
}

// W: [K=768][Ncols] fp32 -> WT: [Ncols][768] bf16
__global__ __launch_bounds__(256) void cast_wt_kernel(
    const float* __restrict__ W, __hip_bfloat16* __restrict__ WT, int Ncols)
{
    const int e  = blockIdx.x * 256 + threadIdx.x;    // Ncols*96 threads
    const int n  = e / 96;
    const int k8 = (e - n * 96) * 8;
    union { short8 s; __hip_bfloat16 h[8]; } u;
#pragma unroll
    for (int j = 0; j < 8; ++j)
        u.h[j] = __float2bfloat16(W[(size_t)(k8 + j) * Ncols + n]);
    *(short8*)(WT + (size_t)n * CC + k8) = u.s;
}

// ---------------------------------------------------------------------------
// One-time V transpose: qkv V-columns [key][d] -> VT [b][h][d][KP keys] bf16.
// Keys in [N1, KP) are zeroed. Grid (20, HH, BB).
// ---------------------------------------------------------------------------
__global__ __launch_bounds__(256) void transpose_v_kernel(
    const __hip_bfloat16* __restrict__ qkv, __hip_bfloat16* __restrict__ vt)
{
    __shared__ short Ls[64 * 72];
    const int t  = threadIdx.x;
    const int kt = blockIdx.x, h = blockIdx.y, b = blockIdx.z;
    const __hip_bfloat16* vb = qkv + (size_t)b * N1 * N_QKV + 2 * CC + h * DH;

#pragma unroll
    for (int i = 0; i < 2; ++i) {
        const int c   = t + 256 * i;          // 512 chunks of 16B = 8KB tile
        const int key = c >> 3;
        const int d8  = (c & 7) * 8;
        const int kg  = kt * 64 + key;
        union { short8 s; short hh[8]; } u;
        if (kg < N1) {
            u.s = *(const short8*)(vb + (size_t)kg * N_QKV + d8);
        } else {
#pragma unroll
            for (int j = 0; j < 8; ++j) u.hh[j] = 0;
        }
#pragma unroll
        for (int j = 0; j < 8; ++j) Ls[(d8 + j) * 72 + key] = u.hh[j];
    }
    __syncthreads();
    __hip_bfloat16* ob = vt + (size_t)(b * HH + h) * 64 * KP + kt * 64;
#pragma unroll
    for (int i = 0; i < 2; ++i) {
        const int c  = t + 256 * i;
        const int d  = c >> 3;
        const int k8 = (c & 7) * 8;
        if (kt * 64 + k8 < KP)               // last k-tile only writes 8 keys/row
            *(short8*)(ob + (size_t)d * KP + k8) = *(const short8*)&Ls[d * 72 + k8];
    }
}

// ---------------------------------------------------------------------------
// m97-style MFMA GEMM (proven R1 structure): C = A . BT^T.  A [M][K] bf16
// (row stride lda), BT [N][K] bf16 row-major. 128x128 tile, BK=32,
// 256 threads (4 waves, 64x64 each), global_load_lds width-16 staging,
// 2-barrier K-loop. Bijective XCD-aware block swizzle (T1/m204) so each
// XCD owns a contiguous run of M-panels -> A rows L2-resident per XCD.
// ---------------------------------------------------------------------------
template <bool WRITE_BF16, bool QSCALE>
__global__ __launch_bounds__(256) void mfma_gemm_bt(
    const __hip_bfloat16* __restrict__ A,
    const __hip_bfloat16* __restrict__ BT,
    void* __restrict__ Cout,
    const float* __restrict__ bias,
    int lda, int K, int ldc)
{
    __shared__ __hip_bfloat16 As[128 * 32];
    __shared__ __hip_bfloat16 Bs[128 * 32];

    const int t    = threadIdx.x;
    const int lane = t & 63;
    const int l15  = lane & 15;
    const int quad = lane >> 4;
    const int w    = t >> 6;
    const int wm   = w & 1;
    const int wn   = w >> 1;

    // bijective XCD swizzle (m204): consecutive tiles on one XCD share A panel.
    const int nwg = gridDim.x * gridDim.y;
    const int lin = blockIdx.y * gridDim.x + blockIdx.x;
    const int qq  = nwg >> 3, rr = nwg & 7;
    const int xcd = lin & 7, off = lin >> 3;
    const int sw  = ((xcd < rr) ? xcd * (qq + 1)
                                : rr * (qq + 1) + (xcd - rr) * qq) + off;
    const int n0 = (sw % gridDim.x) * 128;
    const int m0 = (sw / gridDim.x) * 128;

    // staging: thread t covers byte offsets f0 and f0+4096 of each 8 KB tile
    const int f0 = t * 16;               // bytes; row = f>>6, colbyte = f&63
    const int r0 = f0 >> 6, c0 = (f0 & 63) >> 1;
    const int r1 = (f0 + 4096) >> 6, c1 = c0;

    const __hip_bfloat16* gA0 = A  + (size_t)(m0 + r0) * lda + c0;
    const __hip_bfloat16* gA1 = A  + (size_t)(m0 + r1) * lda + c1;
    const __hip_bfloat16* gB0 = BT + (size_t)(n0 + r0) * K + c0;
    const __hip_bfloat16* gB1 = BT + (size_t)(n0 + r1) * K + c1;

    __hip_bfloat16* lA0 = As + r0 * 32 + c0;
    __hip_bfloat16* lA1 = As + r1 * 32 + c1;
    __hip_bfloat16* lB0 = Bs + r0 * 32 + c0;
    __hip_bfloat16* lB1 = Bs + r1 * 32 + c1;

    f32x4 acc[4][4];
#pragma unroll
    for (int mi = 0; mi < 4; ++mi)
#pragma unroll
        for (int ni = 0; ni < 4; ++ni) {
            acc[mi][ni][0] = 0.f; acc[mi][ni][1] = 0.f;
            acc[mi][ni][2] = 0.f; acc[mi][ni][3] = 0.f;
        }

    for (int k0 = 0; k0 < K; k0 += 32) {
        __syncthreads();                 // previous tile's readers done
        load_lds16(gA0, lA0);
        load_lds16(gA1, lA1);
        load_lds16(gB0, lB0);
        load_lds16(gB1, lB1);
        gA0 += 32; gA1 += 32; gB0 += 32; gB1 += 32;
        __syncthreads();                 // staging drained (vmcnt(0) at barrier)

        short8 af[4], bf_[4];
#pragma unroll
        for (int mi = 0; mi < 4; ++mi)
            af[mi] = *(const short8*)&As[(wm * 64 + mi * 16 + l15) * 32 + quad * 8];
#pragma unroll
        for (int ni = 0; ni < 4; ++ni)
            bf_[ni] = *(const short8*)&Bs[(wn * 64 + ni * 16 + l15) * 32 + quad * 8];
#pragma unroll
        for (int mi = 0; mi < 4; ++mi)
#pragma unroll
            for (int ni = 0; ni < 4; ++ni)
                acc[mi][ni] = __builtin_amdgcn_mfma_f32_16x16x32_bf16(
                    af[mi], bf_[ni], acc[mi][ni], 0, 0, 0);
    }

    // epilogue: C/D layout col = l15, row = quad*4 + reg
#pragma unroll
    for (int mi = 0; mi < 4; ++mi) {
        const int rowb = m0 + wm * 64 + mi * 16 + quad * 4;
#pragma unroll
        for (int ni = 0; ni < 4; ++ni) {
            const int col = n0 + wn * 64 + ni * 16 + l15;
#pragma unroll
            for (int r = 0; r < 4; ++r) {
                const size_t idx = (size_t)(rowb + r) * ldc + col;
                if (WRITE_BF16) {
                    float v = acc[mi][ni][r];
                    if (QSCALE && n0 < CC) v *= SC2F;   // fold softmax scale into Q
                    ((__hip_bfloat16*)Cout)[idx] = __float2bfloat16(v);
                } else {
                    ((float*)Cout)[idx] = acc[mi][ni][r] + bias[col];
                }
            }
        }
    }
}

// ---------------------------------------------------------------------------
// Flash attention, double-buffered K/V staging (T14/T3 2-phase): issue next
// tile's global_load_lds BEFORE computing the current tile, single barrier
// per iteration -> stage latency hides under QK^T+softmax+PV. Conflict-free
// XOR-swizzled LDS, per-wave swizzled P tile, max-free exp2 softmax (scale
// folded into Q), setprio around MFMA clusters, XCD swizzle for K/V L2
// residency. Output written into qkv's dead V-columns.
// ---------------------------------------------------------------------------
__global__ __launch_bounds__(256, 4) void attn_mfma_kernel(
    const __hip_bfloat16* qkv,
    const __hip_bfloat16* __restrict__ vt,
    __hip_bfloat16* ao)                  // = qkv + 2*CC (V-column base)
{
    __shared__ __hip_bfloat16 Ks[2][64 * 64];   // [key][d], 16B units XOR-swz by key&7
    __shared__ __hip_bfloat16 Vs[2][64 * 64];   // [d][key], 16B units XOR-swz by d&7
    __shared__ short Pl[4 * 16 * 64];           // per-wave [q][k], swizzled

    const int t    = threadIdx.x;
    const int l15  = t & 15;
    const int quad = (t >> 4) & 3;
    const int w    = t >> 6;
    const int swz  = l15 & 7;

    // XCD swizzle: XCD g = lin%8 handles 24 (b,h) pairs with all 16 q-tiles
    // each -> K/VT panels (~320 KB/pair) L2-resident per XCD.
    const int L    = blockIdx.x + 16 * (blockIdx.y + 12 * blockIdx.z);
    const int g    = L & 7, s = L >> 3;
    const int pair = g * 24 + (s >> 4);
    const int qt   = s & 15;
    const int h    = pair % 12;
    const int b    = pair / 12;

    const size_t rowbase = (size_t)b * N1;
    const __hip_bfloat16* qb  = qkv + rowbase * N_QKV + h * DH;
    const __hip_bfloat16* kb  = qkv + rowbase * N_QKV + CC + h * DH;
    const __hip_bfloat16* vtb = vt + (size_t)(b * HH + h) * 64 * KP;

    const int cA = t,       rA = cA >> 3, uA = (cA & 7) ^ (rA & 7);
    const int cB = t + 256, rB = cB >> 3, uB = (cB & 7) ^ (rB & 7);

#define ASTAGE(bi, k0) do {                                                        \
        load_lds16(kb  + (size_t)((k0) + rA) * N_QKV + uA * 8, (char*)&Ks[(bi)][0] + cA * 16); \
        load_lds16(kb  + (size_t)((k0) + rB) * N_QKV + uB * 8, (char*)&Ks[(bi)][0] + cB * 16); \
        load_lds16(vtb + (size_t)rA * KP + (k0) + uA * 8,      (char*)&Vs[(bi)][0] + cA * 16); \
        load_lds16(vtb + (size_t)rB * KP + (k0) + uB * 8,      (char*)&Vs[(bi)][0] + cB * 16); \
    } while (0)

    short8 qf[2];
    {
        const size_t qrow = (size_t)(qt * 64 + w * 16 + l15);
#pragma unroll
        for (int ks = 0; ks < 2; ++ks)
            qf[ks] = *(const short8*)(qb + qrow * N_QKV + ks * 32 + quad * 8);
    }

    f32x4 oac[4];
#pragma unroll
    for (int dt = 0; dt < 4; ++dt) {
        oac[dt][0] = 0.f; oac[dt][1] = 0.f; oac[dt][2] = 0.f; oac[dt][3] = 0.f;
    }
    float lrun = 0.f;
    short* Pw = Pl + (w * 16) * 64;

    // prologue: stage tile 0, drain, barrier
    ASTAGE(0, 0);
    __syncthreads();

    int cur = 0;
    for (int k0 = 0; k0 < N1; k0 += 64) {
        // issue next tile's staging first: latency hides under compute (T14)
        if (k0 + 64 < N1) ASTAGE(cur ^ 1, k0 + 64);

        short8 kf[4][2];
#pragma unroll
        for (int mt = 0; mt < 4; ++mt)
#pragma unroll
            for (int ks = 0; ks < 2; ++ks)
                kf[mt][ks] = *(const short8*)
                    &Ks[cur][(mt * 16 + l15) * 64 + ((4 * ks + quad) ^ swz) * 8];

        f32x4 st[4];
#pragma unroll
        for (int mt = 0; mt < 4; ++mt) {
            st[mt][0] = 0.f; st[mt][1] = 0.f; st[mt][2] = 0.f; st[mt][3] = 0.f;
        }
        __builtin_amdgcn_s_setprio(1);
#pragma unroll
        for (int ks = 0; ks < 2; ++ks)
#pragma unroll
            for (int mt = 0; mt < 4; ++mt)
                st[mt] = __builtin_amdgcn_mfma_f32_16x16x32_bf16(
                    kf[mt][ks], qf[ks], st[mt], 0, 0, 0);
        __builtin_amdgcn_s_setprio(0);

        // max-free softmax: scale folded into Q, exp2 args bounded, so no
        // running-max tracking is needed (T13 with THR=inf).
        if (k0 + 64 > N1) {              // mask padded keys (last iter only)
#pragma unroll
            for (int mt = 0; mt < 4; ++mt)
#pragma unroll
                for (int r = 0; r < 4; ++r)
                    if (k0 + mt * 16 + quad * 4 + r >= N1) st[mt][r] = -1e30f;
        }
        float rsum = 0.f;
#pragma unroll
        for (int mt = 0; mt < 4; ++mt)
#pragma unroll
            for (int r = 0; r < 4; ++r) {
                const float p = exp2f(st[mt][r]);
                st[mt][r] = p;
                rsum += p;
            }
        rsum += __shfl_xor(rsum, 16);
        rsum += __shfl_xor(rsum, 32);
        lrun += rsum;

        // P -> per-wave swizzled LDS tile (8B writes, conflict-free)
#pragma unroll
        for (int mt = 0; mt < 4; ++mt) {
            union { unsigned long long u; __hip_bfloat16 hh[4]; } pk;
#pragma unroll
            for (int r = 0; r < 4; ++r) pk.hh[r] = __float2bfloat16(st[mt][r]);
            const int unit = (2 * mt + (quad >> 1)) ^ swz;
            *(unsigned long long*)&Pw[l15 * 64 + unit * 8 + (quad & 1) * 4] = pk.u;
        }

        __builtin_amdgcn_s_setprio(1);
#pragma unroll
        for (int ks = 0; ks < 2; ++ks) {
            const short8 pf = *(const short8*)
                &Pw[l15 * 64 + ((4 * ks + quad) ^ swz) * 8];
#pragma unroll
            for (int dt = 0; dt < 4; ++dt) {
                const short8 vf = *(const short8*)
                    &Vs[cur][(l15 + 16 * dt) * 64 + ((4 * ks + quad) ^ swz) * 8];
                oac[dt] = __builtin_amdgcn_mfma_f32_16x16x32_bf16(pf, vf, oac[dt], 0, 0, 0);
            }
        }
        __builtin_amdgcn_s_setprio(0);

        // single barrier per iter: drains my stage loads (vmcnt0) and seals
        // buf[cur] (all readers done) before its next overwrite.
        __syncthreads();
        cur ^= 1;
    }
#undef ASTAGE

    const float li = 1.0f / lrun;
#pragma unroll
    for (int r = 0; r < 4; ++r) {
        const float ir = __shfl(li, quad * 4 + r);
        const int qrow = qt * 64 + w * 16 + quad * 4 + r;
        __hip_bfloat16* orow = ao + ((size_t)b * NN + qrow) * N_QKV + h * DH;
#pragma unroll
        for (int dt = 0; dt < 4; ++dt)
            orow[l15 + 16 * dt] = __float2bfloat16(oac[dt][r] * ir);
    }
}

// ---------------------------------------------------------------------------
extern "C" void kernel_launch(void* const* d_in, const int* in_sizes, int n_in,
                              void* d_out, int out_size, void* d_ws, size_t ws_size,
                              hipStream_t stream) {
    const float* x      = (const float*)d_in[0];
    const float* sct    = (const float*)d_in[1];
    const float* W_qkv  = (const float*)d_in[2];
    const float* W_proj = (const float*)d_in[3];
    const float* b_proj = (const float*)d_in[4];
    float* out = (float*)d_out;

    // ws layout (bytes), total 125.0 MB (same as R1-proven):
    //   [0, 30.08M):    xt bf16 [19584][768]  -> later reused as VT bf16
    //                   [192*64][1224] (identical size: 30,081,024 B)
    //   [30.08M, 120.3M): qkv bf16 [19584][2304]; attention output is written
    //                     into the (dead after transpose) V columns [1536..2304)
    //   then WT_qkv bf16 [2304][768], WT_proj bf16 [768][768]
    char* p = (char*)d_ws;
    __hip_bfloat16* xt      = (__hip_bfloat16*)p;
    __hip_bfloat16* vtg     = (__hip_bfloat16*)p;            // aliases xt (dead)
    __hip_bfloat16* qkv     = (__hip_bfloat16*)(p + (size_t)MPAD * CC * 2);
    __hip_bfloat16* WTqkv   = (__hip_bfloat16*)(p + (size_t)MPAD * CC * 2 + (size_t)MPAD * N_QKV * 2);
    __hip_bfloat16* WTproj  = WTqkv + (size_t)N_QKV * CC;
    __hip_bfloat16* ao      = qkv + 2 * CC;                  // attn out, stride N_QKV

    cast_xt_kernel<<<MPAD * 96 / 256, 256, 0, stream>>>(x, sct, xt);
    cast_wt_kernel<<<N_QKV * 96 / 256, 256, 0, stream>>>(W_qkv, WTqkv, N_QKV);
    cast_wt_kernel<<<CC * 96 / 256, 256, 0, stream>>>(W_proj, WTproj, CC);

    mfma_gemm_bt<true, true><<<dim3(N_QKV / 128, MPAD / 128), 256, 0, stream>>>(
        xt, WTqkv, qkv, nullptr, CC, CC, N_QKV);
    transpose_v_kernel<<<dim3((N1 + 63) / 64, HH, BB), 256, 0, stream>>>(qkv, vtg);
    attn_mfma_kernel<<<dim3(NN / 64, HH, BB), 256, 0, stream>>>(qkv, vtg, ao);
    mfma_gemm_bt<false, false><<<dim3(CC / 128, M_PROJ / 128), 256, 0, stream>>>(
        ao, WTproj, out, b_proj, N_QKV, CC, CC);
}

// Round 5
// 347.312 us; speedup vs baseline: 1.1502x; 1.1502x over previous
//
#include <hip/hip_runtime.h>
#include <hip/hip_bf16.h>

// Problem constants
#define BB 16
#define NN 1024
#define CC 768
#define HH 12
#define DH 64
#define NSC 196
#define N1 1220              // NN + NSC
#define MPAD 19584           // 153*128, padded row count of xt
#define M_QKV (BB * N1)      // 19520 (valid rows)
#define N_QKV (3 * CC)       // 2304
#define M_PROJ (BB * NN)     // 16384
#define KP 1224              // VT padded key count; 192*64*KP*2 B == MPAD*CC*2 B exactly

typedef __attribute__((ext_vector_type(8))) short short8;   // 8 bf16 = 4 VGPRs
typedef __attribute__((ext_vector_type(4))) float f32x4;

#define SC2F 0.18033688011f   // 0.125 * log2(e): folded into Q, softmax in exp2 domain

__device__ __forceinline__ void load_lds16(const void* g, void* l) {
    __builtin_amdgcn_global_load_lds(
        (__attribute__((address_space(1))) void*)(g),
        (__attribute__((address_space(3))) void*)(l),
        16, 0, 0);
}

// ---------------------------------------------------------------------------
// Cast kernels (one-time): build bf16 xt (concat + zero-pad) and transposed
// bf16 weights so GEMM B operand is row-major [n][k].
// ---------------------------------------------------------------------------
__global__ __launch_bounds__(256) void cast_xt_kernel(
    const float* __restrict__ x, const float* __restrict__ sct,
    __hip_bfloat16* __restrict__ xt)
{
    const int e   = blockIdx.x * 256 + threadIdx.x;   // MPAD*96 threads
    const int row = e / 96;
    const int c8  = (e - row * 96) * 8;
    union { short8 s; __hip_bfloat16 h[8]; } u;
    if (row < M_QKV) {
        const int b  = row / N1;
        const int rr = row - b * N1;
        const float* src = (rr < NN)
            ? x   + ((size_t)b * NN + rr) * CC + c8
            : sct + (size_t)(rr - NN) * CC + c8;
        const float4 v0 = *(const float4*)src;
        const float4 v1 = *(const float4*)(src + 4);
        u.h[0] = __float2bfloat16(v0.x); u.h[1] = __float2bfloat16(v0.y);
        u.h[2] = __float2bfloat16(v0.z); u.h[3] = __float2bfloat16(v0.w);
        u.h[4] = __float2bfloat16(v1.x); u.h[5] = __float2bfloat16(v1.y);
        u.h[6] = __float2bfloat16(v1.z); u.h[7] = __float2bfloat16(v1.w);
    } else {
#pragma unroll
        for (int j = 0; j < 8; ++j) u.h[j] = __float2bfloat16(0.f);
    }
    *(short8*)(xt + (size_t)row * CC + c8) = u.s;
}

// W: [K=768][Ncols] fp32 -> WT: [Ncols][768] bf16
__global__ __launch_bounds__(256) void cast_wt_kernel(
    const float* __restrict__ W, __hip_bfloat16* __restrict__ WT, int Ncols)
{
    const int e  = blockIdx.x * 256 + threadIdx.x;    // Ncols*96 threads
    const int n  = e / 96;
    const int k8 = (e - n * 96) * 8;
    union { short8 s; __hip_bfloat16 h[8]; } u;
#pragma unroll
    for (int j = 0; j < 8; ++j)
        u.h[j] = __float2bfloat16(W[(size_t)(k8 + j) * Ncols + n]);
    *(short8*)(WT + (size_t)n * CC + k8) = u.s;
}

// ---------------------------------------------------------------------------
// One-time V transpose: qkv V-columns [key][d] -> VT [b][h][d][KP keys] bf16.
// Keys in [N1, KP) are zeroed. Grid (20, HH, BB).
// ---------------------------------------------------------------------------
__global__ __launch_bounds__(256) void transpose_v_kernel(
    const __hip_bfloat16* __restrict__ qkv, __hip_bfloat16* __restrict__ vt)
{
    __shared__ short Ls[64 * 72];
    const int t  = threadIdx.x;
    const int kt = blockIdx.x, h = blockIdx.y, b = blockIdx.z;
    const __hip_bfloat16* vb = qkv + (size_t)b * N1 * N_QKV + 2 * CC + h * DH;

#pragma unroll
    for (int i = 0; i < 2; ++i) {
        const int c   = t + 256 * i;          // 512 chunks of 16B = 8KB tile
        const int key = c >> 3;
        const int d8  = (c & 7) * 8;
        const int kg  = kt * 64 + key;
        union { short8 s; short hh[8]; } u;
        if (kg < N1) {
            u.s = *(const short8*)(vb + (size_t)kg * N_QKV + d8);
        } else {
#pragma unroll
            for (int j = 0; j < 8; ++j) u.hh[j] = 0;
        }
#pragma unroll
        for (int j = 0; j < 8; ++j) Ls[(d8 + j) * 72 + key] = u.hh[j];
    }
    __syncthreads();
    __hip_bfloat16* ob = vt + (size_t)(b * HH + h) * 64 * KP + kt * 64;
#pragma unroll
    for (int i = 0; i < 2; ++i) {
        const int c  = t + 256 * i;
        const int d  = c >> 3;
        const int k8 = (c & 7) * 8;
        if (kt * 64 + k8 < KP)               // last k-tile only writes 8 keys/row
            *(short8*)(ob + (size_t)d * KP + k8) = *(const short8*)&Ls[d * 72 + k8];
    }
}

// ---------------------------------------------------------------------------
// MFMA GEMM, BK=64: C = A . BT^T.  A [M][K] bf16 (row stride lda), BT [N][K]
// bf16 row-major. 128x128 tile, 256 threads (4 waves, 64x64 each),
// global_load_lds width-16 staging, 2-barrier loop -> 12 drains at K=768
// (half of BK=32). Rows are 128 B so LDS uses the rule-#21 both-sides XOR
// swizzle (16B unit ^= row&7, pre-swizzled global source) -> ds_read_b128
// is 2-way (free, m136) instead of the m201 16-way conflict.
// Bijective XCD swizzle (m204) keeps each XCD's A-panels L2-resident.
// ---------------------------------------------------------------------------
template <bool WRITE_BF16, bool QSCALE>
__global__ __launch_bounds__(256) void mfma_gemm_bt(
    const __hip_bfloat16* __restrict__ A,
    const __hip_bfloat16* __restrict__ BT,
    void* __restrict__ Cout,
    const float* __restrict__ bias,
    int lda, int K, int ldc)
{
    __shared__ __hip_bfloat16 As[128 * 64];   // 16 KB
    __shared__ __hip_bfloat16 Bs[128 * 64];   // 16 KB

    const int t    = threadIdx.x;
    const int lane = t & 63;
    const int l15  = lane & 15;
    const int quad = lane >> 4;
    const int w    = t >> 6;
    const int wm   = w & 1;
    const int wn   = w >> 1;
    const int swz  = l15 & 7;

    // bijective XCD swizzle (m204)
    const int nwg = gridDim.x * gridDim.y;
    const int lin = blockIdx.y * gridDim.x + blockIdx.x;
    const int qq  = nwg >> 3, rr = nwg & 7;
    const int xcd = lin & 7, off = lin >> 3;
    const int sw  = ((xcd < rr) ? xcd * (qq + 1)
                                : rr * (qq + 1) + (xcd - rr) * qq) + off;
    const int n0 = (sw % gridDim.x) * 128;
    const int m0 = (sw / gridDim.x) * 128;

    // Staging: thread t covers chunks c = t + 256*i (i=0..3), 16 B each.
    // chunk c: row = c>>3 (= t>>3 + 32*i), unit = c&7. Source unit is
    // XOR-pre-swizzled by row&7 (row&7 == (t>>3)&7 for all 4 chunks since
    // rows differ by 32). LDS dest is linear: element c*8 = row*64 + unit*8.
    const int rr0 = t >> 3;                          // 0..31
    const int uu  = ((t & 7) ^ (rr0 & 7)) * 8;       // source element offset

    const __hip_bfloat16* gA = A  + (size_t)(m0 + rr0) * lda + uu;
    const __hip_bfloat16* gB = BT + (size_t)(n0 + rr0) * K   + uu;
    __hip_bfloat16* lA = As + t * 8;
    __hip_bfloat16* lB = Bs + t * 8;

    f32x4 acc[4][4];
#pragma unroll
    for (int mi = 0; mi < 4; ++mi)
#pragma unroll
        for (int ni = 0; ni < 4; ++ni) {
            acc[mi][ni][0] = 0.f; acc[mi][ni][1] = 0.f;
            acc[mi][ni][2] = 0.f; acc[mi][ni][3] = 0.f;
        }

    for (int k0 = 0; k0 < K; k0 += 64) {
        __syncthreads();                 // previous tile's readers done
        load_lds16(gA,            lA);
        load_lds16(gA + 32 * lda, lA + 2048);
        load_lds16(gA + 64 * lda, lA + 4096);
        load_lds16(gA + 96 * lda, lA + 6144);
        load_lds16(gB,            lB);
        load_lds16(gB + 32 * K,   lB + 2048);
        load_lds16(gB + 64 * K,   lB + 4096);
        load_lds16(gB + 96 * K,   lB + 6144);
        gA += 64; gB += 64;
        __syncthreads();                 // staging drained (vmcnt(0) at barrier)

#pragma unroll
        for (int ks = 0; ks < 2; ++ks) {
            short8 af[4], bf_[4];
            const int u = ((ks * 4 + quad) ^ swz) * 8;   // swizzled unit offset
#pragma unroll
            for (int mi = 0; mi < 4; ++mi)
                af[mi] = *(const short8*)&As[(wm * 64 + mi * 16 + l15) * 64 + u];
#pragma unroll
            for (int ni = 0; ni < 4; ++ni)
                bf_[ni] = *(const short8*)&Bs[(wn * 64 + ni * 16 + l15) * 64 + u];
#pragma unroll
            for (int mi = 0; mi < 4; ++mi)
#pragma unroll
                for (int ni = 0; ni < 4; ++ni)
                    acc[mi][ni] = __builtin_amdgcn_mfma_f32_16x16x32_bf16(
                        af[mi], bf_[ni], acc[mi][ni], 0, 0, 0);
        }
    }

    // epilogue: C/D layout col = l15, row = quad*4 + reg
#pragma unroll
    for (int mi = 0; mi < 4; ++mi) {
        const int rowb = m0 + wm * 64 + mi * 16 + quad * 4;
#pragma unroll
        for (int ni = 0; ni < 4; ++ni) {
            const int col = n0 + wn * 64 + ni * 16 + l15;
#pragma unroll
            for (int r = 0; r < 4; ++r) {
                const size_t idx = (size_t)(rowb + r) * ldc + col;
                if (WRITE_BF16) {
                    float v = acc[mi][ni][r];
                    if (QSCALE && n0 < CC) v *= SC2F;   // fold softmax scale into Q
                    ((__hip_bfloat16*)Cout)[idx] = __float2bfloat16(v);
                } else {
                    ((float*)Cout)[idx] = acc[mi][ni][r] + bias[col];
                }
            }
        }
    }
}

// ---------------------------------------------------------------------------
// Flash attention: Ks single-buffered + mid-barrier, Vs double-buffered.
// Per iter: read kf->regs, QK^T (reg-only), mid-barrier (no vm drain: no
// outstanding vmem), THEN issue next tile's staging -> its L2 latency hides
// under softmax+P+PV; end barrier drains and seals. LDS 32 KB -> 5 blk/CU
// (vs R4's 40 KB / 4 blk). Conflict-free XOR-swizzled LDS, per-wave P tile,
// max-free exp2 softmax (scale folded into Q), setprio, XCD swizzle.
// ---------------------------------------------------------------------------
__global__ __launch_bounds__(256, 4) void attn_mfma_kernel(
    const __hip_bfloat16* qkv,
    const __hip_bfloat16* __restrict__ vt,
    __hip_bfloat16* ao)                  // = qkv + 2*CC (V-column base)
{
    __shared__ __hip_bfloat16 Ks[64 * 64];      // 8 KB, single
    __shared__ __hip_bfloat16 Vs[2][64 * 64];   // 16 KB, double
    __shared__ short Pl[4 * 16 * 64];           // 8 KB, per-wave

    const int t    = threadIdx.x;
    const int l15  = t & 15;
    const int quad = (t >> 4) & 3;
    const int w    = t >> 6;
    const int swz  = l15 & 7;

    // XCD swizzle: each XCD owns 24 (b,h) pairs with all 16 q-tiles ->
    // K/VT panels (~320 KB/pair) L2-resident per XCD.
    const int L    = blockIdx.x + 16 * (blockIdx.y + 12 * blockIdx.z);
    const int g    = L & 7, s = L >> 3;
    const int pair = g * 24 + (s >> 4);
    const int qt   = s & 15;
    const int h    = pair % 12;
    const int b    = pair / 12;

    const size_t rowbase = (size_t)b * N1;
    const __hip_bfloat16* qb  = qkv + rowbase * N_QKV + h * DH;
    const __hip_bfloat16* kb  = qkv + rowbase * N_QKV + CC + h * DH;
    const __hip_bfloat16* vtb = vt + (size_t)(b * HH + h) * 64 * KP;

    const int cA = t,       rA = cA >> 3, uA = (cA & 7) ^ (rA & 7);
    const int cB = t + 256, rB = cB >> 3, uB = (cB & 7) ^ (rB & 7);

#define KSTAGE(k0) do {                                                            \
        load_lds16(kb + (size_t)((k0) + rA) * N_QKV + uA * 8, (char*)Ks + cA * 16); \
        load_lds16(kb + (size_t)((k0) + rB) * N_QKV + uB * 8, (char*)Ks + cB * 16); \
    } while (0)
#define VSTAGE(bi, k0) do {                                                        \
        load_lds16(vtb + (size_t)rA * KP + (k0) + uA * 8, (char*)&Vs[(bi)][0] + cA * 16); \
        load_lds16(vtb + (size_t)rB * KP + (k0) + uB * 8, (char*)&Vs[(bi)][0] + cB * 16); \
    } while (0)

    short8 qf[2];
    {
        const size_t qrow = (size_t)(qt * 64 + w * 16 + l15);
#pragma unroll
        for (int ks = 0; ks < 2; ++ks)
            qf[ks] = *(const short8*)(qb + qrow * N_QKV + ks * 32 + quad * 8);
    }

    f32x4 oac[4];
#pragma unroll
    for (int dt = 0; dt < 4; ++dt) {
        oac[dt][0] = 0.f; oac[dt][1] = 0.f; oac[dt][2] = 0.f; oac[dt][3] = 0.f;
    }
    float lrun = 0.f;
    short* Pw = Pl + (w * 16) * 64;

    // prologue: stage tile 0 (K and V), drain, barrier
    KSTAGE(0);
    VSTAGE(0, 0);
    __syncthreads();

    int cur = 0;
    for (int k0 = 0; k0 < N1; k0 += 64) {
        // ---- read K fragments to regs, QK^T (register-only) ----
        short8 kf[4][2];
#pragma unroll
        for (int mt = 0; mt < 4; ++mt)
#pragma unroll
            for (int ks = 0; ks < 2; ++ks)
                kf[mt][ks] = *(const short8*)
                    &Ks[(mt * 16 + l15) * 64 + ((4 * ks + quad) ^ swz) * 8];

        f32x4 st[4];
#pragma unroll
        for (int mt = 0; mt < 4; ++mt) {
            st[mt][0] = 0.f; st[mt][1] = 0.f; st[mt][2] = 0.f; st[mt][3] = 0.f;
        }
        __builtin_amdgcn_s_setprio(1);
#pragma unroll
        for (int ks = 0; ks < 2; ++ks)
#pragma unroll
            for (int mt = 0; mt < 4; ++mt)
                st[mt] = __builtin_amdgcn_mfma_f32_16x16x32_bf16(
                    kf[mt][ks], qf[ks], st[mt], 0, 0, 0);
        __builtin_amdgcn_s_setprio(0);

        // ---- mid-barrier: all waves done reading Ks (no vmem outstanding,
        // so the implicit vmcnt(0) is free) ----
        __syncthreads();

        // ---- issue next tile's staging; latency hides under softmax+PV ----
        if (k0 + 64 < N1) {
            KSTAGE(k0 + 64);
            VSTAGE(cur ^ 1, k0 + 64);
        }

        // ---- max-free softmax: scale folded into Q, exp2 args bounded ----
        if (k0 + 64 > N1) {              // mask padded keys (last iter only)
#pragma unroll
            for (int mt = 0; mt < 4; ++mt)
#pragma unroll
                for (int r = 0; r < 4; ++r)
                    if (k0 + mt * 16 + quad * 4 + r >= N1) st[mt][r] = -1e30f;
        }
        float rsum = 0.f;
#pragma unroll
        for (int mt = 0; mt < 4; ++mt)
#pragma unroll
            for (int r = 0; r < 4; ++r) {
                const float p = exp2f(st[mt][r]);
                st[mt][r] = p;
                rsum += p;
            }
        rsum += __shfl_xor(rsum, 16);
        rsum += __shfl_xor(rsum, 32);
        lrun += rsum;

        // P -> per-wave swizzled LDS tile (8B writes, conflict-free)
#pragma unroll
        for (int mt = 0; mt < 4; ++mt) {
            union { unsigned long long u; __hip_bfloat16 hh[4]; } pk;
#pragma unroll
            for (int r = 0; r < 4; ++r) pk.hh[r] = __float2bfloat16(st[mt][r]);
            const int unit = (2 * mt + (quad >> 1)) ^ swz;
            *(unsigned long long*)&Pw[l15 * 64 + unit * 8 + (quad & 1) * 4] = pk.u;
        }

        __builtin_amdgcn_s_setprio(1);
#pragma unroll
        for (int ks = 0; ks < 2; ++ks) {
            const short8 pf = *(const short8*)
                &Pw[l15 * 64 + ((4 * ks + quad) ^ swz) * 8];
#pragma unroll
            for (int dt = 0; dt < 4; ++dt) {
                const short8 vf = *(const short8*)
                    &Vs[cur][(l15 + 16 * dt) * 64 + ((4 * ks + quad) ^ swz) * 8];
                oac[dt] = __builtin_amdgcn_mfma_f32_16x16x32_bf16(pf, vf, oac[dt], 0, 0, 0);
            }
        }
        __builtin_amdgcn_s_setprio(0);

        // end barrier: drains my staging (vmcnt(0)) -> Ks/Vs[cur^1] sealed
        // for the next iteration; also ends this iter's Ks/Pl read window.
        __syncthreads();
        cur ^= 1;
    }
#undef KSTAGE
#undef VSTAGE

    const float li = 1.0f / lrun;
#pragma unroll
    for (int r = 0; r < 4; ++r) {
        const float ir = __shfl(li, quad * 4 + r);
        const int qrow = qt * 64 + w * 16 + quad * 4 + r;
        __hip_bfloat16* orow = ao + ((size_t)b * NN + qrow) * N_QKV + h * DH;
#pragma unroll
        for (int dt = 0; dt < 4; ++dt)
            orow[l15 + 16 * dt] = __float2bfloat16(oac[dt][r] * ir);
    }
}

// ---------------------------------------------------------------------------
extern "C" void kernel_launch(void* const* d_in, const int* in_sizes, int n_in,
                              void* d_out, int out_size, void* d_ws, size_t ws_size,
                              hipStream_t stream) {
    const float* x      = (const float*)d_in[0];
    const float* sct    = (const float*)d_in[1];
    const float* W_qkv  = (const float*)d_in[2];
    const float* W_proj = (const float*)d_in[3];
    const float* b_proj = (const float*)d_in[4];
    float* out = (float*)d_out;

    // ws layout (bytes), total 125.0 MB (same as R1-proven):
    //   [0, 30.08M):    xt bf16 [19584][768]  -> later reused as VT bf16
    //                   [192*64][1224] (identical size: 30,081,024 B)
    //   [30.08M, 120.3M): qkv bf16 [19584][2304]; attention output is written
    //                     into the (dead after transpose) V columns [1536..2304)
    //   then WT_qkv bf16 [2304][768], WT_proj bf16 [768][768]
    char* p = (char*)d_ws;
    __hip_bfloat16* xt      = (__hip_bfloat16*)p;
    __hip_bfloat16* vtg     = (__hip_bfloat16*)p;            // aliases xt (dead)
    __hip_bfloat16* qkv     = (__hip_bfloat16*)(p + (size_t)MPAD * CC * 2);
    __hip_bfloat16* WTqkv   = (__hip_bfloat16*)(p + (size_t)MPAD * CC * 2 + (size_t)MPAD * N_QKV * 2);
    __hip_bfloat16* WTproj  = WTqkv + (size_t)N_QKV * CC;
    __hip_bfloat16* ao      = qkv + 2 * CC;                  // attn out, stride N_QKV

    cast_xt_kernel<<<MPAD * 96 / 256, 256, 0, stream>>>(x, sct, xt);
    cast_wt_kernel<<<N_QKV * 96 / 256, 256, 0, stream>>>(W_qkv, WTqkv, N_QKV);
    cast_wt_kernel<<<CC * 96 / 256, 256, 0, stream>>>(W_proj, WTproj, CC);

    mfma_gemm_bt<true, true><<<dim3(N_QKV / 128, MPAD / 128), 256, 0, stream>>>(
        xt, WTqkv, qkv, nullptr, CC, CC, N_QKV);
    transpose_v_kernel<<<dim3((N1 + 63) / 64, HH, BB), 256, 0, stream>>>(qkv, vtg);
    attn_mfma_kernel<<<dim3(NN / 64, HH, BB), 256, 0, stream>>>(qkv, vtg, ao);
    mfma_gemm_bt<false, false><<<dim3(CC / 128, M_PROJ / 128), 256, 0, stream>>>(
        ao, WTproj, out, b_proj, N_QKV, CC, CC);
}

// Round 6
// 347.297 us; speedup vs baseline: 1.1502x; 1.0000x over previous
//
#include <hip/hip_runtime.h>
#include <hip/hip_bf16.h>

// Problem constants
#define BB 16
#define NN 1024
#define CC 768
#define HH 12
#define DH 64
#define NSC 196
#define N1 1220              // NN + NSC
#define MPAD 19584           // 153*128, padded row count of xt
#define M_QKV (BB * N1)      // 19520 (valid rows)
#define N_QKV (3 * CC)       // 2304
#define M_PROJ (BB * NN)     // 16384
#define KP 1224              // VT padded key count; 192*64*KP*2 B == MPAD*CC*2 B exactly

typedef __attribute__((ext_vector_type(8))) short short8;   // 8 bf16 = 4 VGPRs
typedef __attribute__((ext_vector_type(4))) float f32x4;

#define SC2F 0.125f   // softmax scale folded into Q; softmax uses native __expf

__device__ __forceinline__ void load_lds16(const void* g, void* l) {
    __builtin_amdgcn_global_load_lds(
        (__attribute__((address_space(1))) void*)(g),
        (__attribute__((address_space(3))) void*)(l),
        16, 0, 0);
}

// ---------------------------------------------------------------------------
// Cast kernels (one-time): build bf16 xt (concat + zero-pad) and transposed
// bf16 weights so GEMM B operand is row-major [n][k].
// ---------------------------------------------------------------------------
__global__ __launch_bounds__(256) void cast_xt_kernel(
    const float* __restrict__ x, const float* __restrict__ sct,
    __hip_bfloat16* __restrict__ xt)
{
    const int e   = blockIdx.x * 256 + threadIdx.x;   // MPAD*96 threads
    const int row = e / 96;
    const int c8  = (e - row * 96) * 8;
    union { short8 s; __hip_bfloat16 h[8]; } u;
    if (row < M_QKV) {
        const int b  = row / N1;
        const int rr = row - b * N1;
        const float* src = (rr < NN)
            ? x   + ((size_t)b * NN + rr) * CC + c8
            : sct + (size_t)(rr - NN) * CC + c8;
        const float4 v0 = *(const float4*)src;
        const float4 v1 = *(const float4*)(src + 4);
        u.h[0] = __float2bfloat16(v0.x); u.h[1] = __float2bfloat16(v0.y);
        u.h[2] = __float2bfloat16(v0.z); u.h[3] = __float2bfloat16(v0.w);
        u.h[4] = __float2bfloat16(v1.x); u.h[5] = __float2bfloat16(v1.y);
        u.h[6] = __float2bfloat16(v1.z); u.h[7] = __float2bfloat16(v1.w);
    } else {
#pragma unroll
        for (int j = 0; j < 8; ++j) u.h[j] = __float2bfloat16(0.f);
    }
    *(short8*)(xt + (size_t)row * CC + c8) = u.s;
}

// W: [K=768][Ncols] fp32 -> WT: [Ncols][768] bf16
__global__ __launch_bounds__(256) void cast_wt_kernel(
    const float* __restrict__ W, __hip_bfloat16* __restrict__ WT, int Ncols)
{
    const int e  = blockIdx.x * 256 + threadIdx.x;    // Ncols*96 threads
    const int n  = e / 96;
    const int k8 = (e - n * 96) * 8;
    union { short8 s; __hip_bfloat16 h[8]; } u;
#pragma unroll
    for (int j = 0; j < 8; ++j)
        u.h[j] = __float2bfloat16(W[(size_t)(k8 + j) * Ncols + n]);
    *(short8*)(WT + (size_t)n * CC + k8) = u.s;
}

// ---------------------------------------------------------------------------
// One-time V transpose: qkv V-columns [key][d] -> VT [b][h][d][KP keys] bf16.
// Keys in [N1, KP) are zeroed. Grid (20, HH, BB).
// ---------------------------------------------------------------------------
__global__ __launch_bounds__(256) void transpose_v_kernel(
    const __hip_bfloat16* __restrict__ qkv, __hip_bfloat16* __restrict__ vt)
{
    __shared__ short Ls[64 * 72];
    const int t  = threadIdx.x;
    const int kt = blockIdx.x, h = blockIdx.y, b = blockIdx.z;
    const __hip_bfloat16* vb = qkv + (size_t)b * N1 * N_QKV + 2 * CC + h * DH;

#pragma unroll
    for (int i = 0; i < 2; ++i) {
        const int c   = t + 256 * i;          // 512 chunks of 16B = 8KB tile
        const int key = c >> 3;
        const int d8  = (c & 7) * 8;
        const int kg  = kt * 64 + key;
        union { short8 s; short hh[8]; } u;
        if (kg < N1) {
            u.s = *(const short8*)(vb + (size_t)kg * N_QKV + d8);
        } else {
#pragma unroll
            for (int j = 0; j < 8; ++j) u.hh[j] = 0;
        }
#pragma unroll
        for (int j = 0; j < 8; ++j) Ls[(d8 + j) * 72 + key] = u.hh[j];
    }
    __syncthreads();
    __hip_bfloat16* ob = vt + (size_t)(b * HH + h) * 64 * KP + kt * 64;
#pragma unroll
    for (int i = 0; i < 2; ++i) {
        const int c  = t + 256 * i;
        const int d  = c >> 3;
        const int k8 = (c & 7) * 8;
        if (kt * 64 + k8 < KP)               // last k-tile only writes 8 keys/row
            *(short8*)(ob + (size_t)d * KP + k8) = *(const short8*)&Ls[d * 72 + k8];
    }
}

// ---------------------------------------------------------------------------
// MFMA GEMM, BK=64: C = A . BT^T.  A [M][K] bf16 (row stride lda), BT [N][K]
// bf16 row-major. 128x128 tile, 256 threads (4 waves, 64x64 each),
// global_load_lds width-16 staging, 2-barrier loop -> 12 drains at K=768.
// Rows are 128 B so LDS uses the rule-#21 both-sides XOR swizzle (16B unit
// ^= row&7, pre-swizzled global source) -> ds_read_b128 is 2-way (free).
// Bijective XCD swizzle (m204) keeps each XCD's A-panels L2-resident.
// ---------------------------------------------------------------------------
template <bool WRITE_BF16, bool QSCALE>
__global__ __launch_bounds__(256) void mfma_gemm_bt(
    const __hip_bfloat16* __restrict__ A,
    const __hip_bfloat16* __restrict__ BT,
    void* __restrict__ Cout,
    const float* __restrict__ bias,
    int lda, int K, int ldc)
{
    __shared__ __hip_bfloat16 As[128 * 64];   // 16 KB
    __shared__ __hip_bfloat16 Bs[128 * 64];   // 16 KB

    const int t    = threadIdx.x;
    const int lane = t & 63;
    const int l15  = lane & 15;
    const int quad = lane >> 4;
    const int w    = t >> 6;
    const int wm   = w & 1;
    const int wn   = w >> 1;
    const int swz  = l15 & 7;

    // bijective XCD swizzle (m204)
    const int nwg = gridDim.x * gridDim.y;
    const int lin = blockIdx.y * gridDim.x + blockIdx.x;
    const int qq  = nwg >> 3, rr = nwg & 7;
    const int xcd = lin & 7, off = lin >> 3;
    const int sw  = ((xcd < rr) ? xcd * (qq + 1)
                                : rr * (qq + 1) + (xcd - rr) * qq) + off;
    const int n0 = (sw % gridDim.x) * 128;
    const int m0 = (sw / gridDim.x) * 128;

    // Staging: thread t covers chunks c = t + 256*i (i=0..3), 16 B each.
    // chunk c: row = c>>3, unit = c&7. Source unit is XOR-pre-swizzled by
    // row&7 (row&7 == (t>>3)&7 for all 4 chunks since rows differ by 32).
    const int rr0 = t >> 3;                          // 0..31
    const int uu  = ((t & 7) ^ (rr0 & 7)) * 8;       // source element offset

    const __hip_bfloat16* gA = A  + (size_t)(m0 + rr0) * lda + uu;
    const __hip_bfloat16* gB = BT + (size_t)(n0 + rr0) * K   + uu;
    __hip_bfloat16* lA = As + t * 8;
    __hip_bfloat16* lB = Bs + t * 8;

    f32x4 acc[4][4];
#pragma unroll
    for (int mi = 0; mi < 4; ++mi)
#pragma unroll
        for (int ni = 0; ni < 4; ++ni) {
            acc[mi][ni][0] = 0.f; acc[mi][ni][1] = 0.f;
            acc[mi][ni][2] = 0.f; acc[mi][ni][3] = 0.f;
        }

    for (int k0 = 0; k0 < K; k0 += 64) {
        __syncthreads();                 // previous tile's readers done
        load_lds16(gA,            lA);
        load_lds16(gA + 32 * lda, lA + 2048);
        load_lds16(gA + 64 * lda, lA + 4096);
        load_lds16(gA + 96 * lda, lA + 6144);
        load_lds16(gB,            lB);
        load_lds16(gB + 32 * K,   lB + 2048);
        load_lds16(gB + 64 * K,   lB + 4096);
        load_lds16(gB + 96 * K,   lB + 6144);
        gA += 64; gB += 64;
        __syncthreads();                 // staging drained (vmcnt(0) at barrier)

#pragma unroll
        for (int ks = 0; ks < 2; ++ks) {
            short8 af[4], bf_[4];
            const int u = ((ks * 4 + quad) ^ swz) * 8;   // swizzled unit offset
#pragma unroll
            for (int mi = 0; mi < 4; ++mi)
                af[mi] = *(const short8*)&As[(wm * 64 + mi * 16 + l15) * 64 + u];
#pragma unroll
            for (int ni = 0; ni < 4; ++ni)
                bf_[ni] = *(const short8*)&Bs[(wn * 64 + ni * 16 + l15) * 64 + u];
#pragma unroll
            for (int mi = 0; mi < 4; ++mi)
#pragma unroll
                for (int ni = 0; ni < 4; ++ni)
                    acc[mi][ni] = __builtin_amdgcn_mfma_f32_16x16x32_bf16(
                        af[mi], bf_[ni], acc[mi][ni], 0, 0, 0);
        }
    }

    // epilogue: C/D layout col = l15, row = quad*4 + reg
#pragma unroll
    for (int mi = 0; mi < 4; ++mi) {
        const int rowb = m0 + wm * 64 + mi * 16 + quad * 4;
#pragma unroll
        for (int ni = 0; ni < 4; ++ni) {
            const int col = n0 + wn * 64 + ni * 16 + l15;
#pragma unroll
            for (int r = 0; r < 4; ++r) {
                const size_t idx = (size_t)(rowb + r) * ldc + col;
                if (WRITE_BF16) {
                    float v = acc[mi][ni][r];
                    if (QSCALE && n0 < CC) v *= SC2F;   // fold softmax scale into Q
                    ((__hip_bfloat16*)Cout)[idx] = __float2bfloat16(v);
                } else {
                    ((float*)Cout)[idx] = acc[mi][ni][r] + bias[col];
                }
            }
        }
    }
}

// ---------------------------------------------------------------------------
// Flash attention: Ks single-buffered + mid-barrier, Vs double-buffered.
// Per iter: read kf->regs, QK^T (reg-only), mid-barrier (free: no vmem
// outstanding), THEN issue next tile's staging -> latency hides under
// softmax+P+PV; end barrier drains and seals. Max-free softmax via native
// __expf (v_mul+v_exp, 2 instrs/elem — libm exp2f's precise path was ~6x
// that and dominated VALUBusy). Conflict-free XOR-swizzled LDS, per-wave
// P tile, setprio, XCD swizzle for K/V L2 residency.
// ---------------------------------------------------------------------------
__global__ __launch_bounds__(256, 4) void attn_mfma_kernel(
    const __hip_bfloat16* qkv,
    const __hip_bfloat16* __restrict__ vt,
    __hip_bfloat16* ao)                  // = qkv + 2*CC (V-column base)
{
    __shared__ __hip_bfloat16 Ks[64 * 64];      // 8 KB, single
    __shared__ __hip_bfloat16 Vs[2][64 * 64];   // 16 KB, double
    __shared__ short Pl[4 * 16 * 64];           // 8 KB, per-wave

    const int t    = threadIdx.x;
    const int l15  = t & 15;
    const int quad = (t >> 4) & 3;
    const int w    = t >> 6;
    const int swz  = l15 & 7;

    // XCD swizzle: each XCD owns 24 (b,h) pairs with all 16 q-tiles ->
    // K/VT panels (~320 KB/pair) L2-resident per XCD.
    const int L    = blockIdx.x + 16 * (blockIdx.y + 12 * blockIdx.z);
    const int g    = L & 7, s = L >> 3;
    const int pair = g * 24 + (s >> 4);
    const int qt   = s & 15;
    const int h    = pair % 12;
    const int b    = pair / 12;

    const size_t rowbase = (size_t)b * N1;
    const __hip_bfloat16* qb  = qkv + rowbase * N_QKV + h * DH;
    const __hip_bfloat16* kb  = qkv + rowbase * N_QKV + CC + h * DH;
    const __hip_bfloat16* vtb = vt + (size_t)(b * HH + h) * 64 * KP;

    const int cA = t,       rA = cA >> 3, uA = (cA & 7) ^ (rA & 7);
    const int cB = t + 256, rB = cB >> 3, uB = (cB & 7) ^ (rB & 7);

#define KSTAGE(k0) do {                                                            \
        load_lds16(kb + (size_t)((k0) + rA) * N_QKV + uA * 8, (char*)Ks + cA * 16); \
        load_lds16(kb + (size_t)((k0) + rB) * N_QKV + uB * 8, (char*)Ks + cB * 16); \
    } while (0)
#define VSTAGE(bi, k0) do {                                                        \
        load_lds16(vtb + (size_t)rA * KP + (k0) + uA * 8, (char*)&Vs[(bi)][0] + cA * 16); \
        load_lds16(vtb + (size_t)rB * KP + (k0) + uB * 8, (char*)&Vs[(bi)][0] + cB * 16); \
    } while (0)

    short8 qf[2];
    {
        const size_t qrow = (size_t)(qt * 64 + w * 16 + l15);
#pragma unroll
        for (int ks = 0; ks < 2; ++ks)
            qf[ks] = *(const short8*)(qb + qrow * N_QKV + ks * 32 + quad * 8);
    }

    f32x4 oac[4];
#pragma unroll
    for (int dt = 0; dt < 4; ++dt) {
        oac[dt][0] = 0.f; oac[dt][1] = 0.f; oac[dt][2] = 0.f; oac[dt][3] = 0.f;
    }
    float lrun = 0.f;
    short* Pw = Pl + (w * 16) * 64;

    // prologue: stage tile 0 (K and V), drain, barrier
    KSTAGE(0);
    VSTAGE(0, 0);
    __syncthreads();

    int cur = 0;
    for (int k0 = 0; k0 < N1; k0 += 64) {
        // ---- read K fragments to regs, QK^T (register-only) ----
        short8 kf[4][2];
#pragma unroll
        for (int mt = 0; mt < 4; ++mt)
#pragma unroll
            for (int ks = 0; ks < 2; ++ks)
                kf[mt][ks] = *(const short8*)
                    &Ks[(mt * 16 + l15) * 64 + ((4 * ks + quad) ^ swz) * 8];

        f32x4 st[4];
#pragma unroll
        for (int mt = 0; mt < 4; ++mt) {
            st[mt][0] = 0.f; st[mt][1] = 0.f; st[mt][2] = 0.f; st[mt][3] = 0.f;
        }
        __builtin_amdgcn_s_setprio(1);
#pragma unroll
        for (int ks = 0; ks < 2; ++ks)
#pragma unroll
            for (int mt = 0; mt < 4; ++mt)
                st[mt] = __builtin_amdgcn_mfma_f32_16x16x32_bf16(
                    kf[mt][ks], qf[ks], st[mt], 0, 0, 0);
        __builtin_amdgcn_s_setprio(0);

        // ---- mid-barrier: all waves done reading Ks (no vmem outstanding,
        // so the implicit vmcnt(0) is free) ----
        __syncthreads();

        // ---- issue next tile's staging; latency hides under softmax+PV ----
        if (k0 + 64 < N1) {
            KSTAGE(k0 + 64);
            VSTAGE(cur ^ 1, k0 + 64);
        }

        // ---- max-free softmax: scale folded into Q, exp args bounded
        // (|S/8| < ~12 -> P < e^12, f32 sum has headroom); native __expf ----
        if (k0 + 64 > N1) {              // mask padded keys (last iter only)
#pragma unroll
            for (int mt = 0; mt < 4; ++mt)
#pragma unroll
                for (int r = 0; r < 4; ++r)
                    if (k0 + mt * 16 + quad * 4 + r >= N1) st[mt][r] = -1e30f;
        }
        float rsum = 0.f;
#pragma unroll
        for (int mt = 0; mt < 4; ++mt)
#pragma unroll
            for (int r = 0; r < 4; ++r) {
                const float p = __expf(st[mt][r]);
                st[mt][r] = p;
                rsum += p;
            }
        rsum += __shfl_xor(rsum, 16);
        rsum += __shfl_xor(rsum, 32);
        lrun += rsum;

        // P -> per-wave swizzled LDS tile (8B writes, conflict-free)
#pragma unroll
        for (int mt = 0; mt < 4; ++mt) {
            union { unsigned long long u; __hip_bfloat16 hh[4]; } pk;
#pragma unroll
            for (int r = 0; r < 4; ++r) pk.hh[r] = __float2bfloat16(st[mt][r]);
            const int unit = (2 * mt + (quad >> 1)) ^ swz;
            *(unsigned long long*)&Pw[l15 * 64 + unit * 8 + (quad & 1) * 4] = pk.u;
        }

        __builtin_amdgcn_s_setprio(1);
#pragma unroll
        for (int ks = 0; ks < 2; ++ks) {
            const short8 pf = *(const short8*)
                &Pw[l15 * 64 + ((4 * ks + quad) ^ swz) * 8];
#pragma unroll
            for (int dt = 0; dt < 4; ++dt) {
                const short8 vf = *(const short8*)
                    &Vs[cur][(l15 + 16 * dt) * 64 + ((4 * ks + quad) ^ swz) * 8];
                oac[dt] = __builtin_amdgcn_mfma_f32_16x16x32_bf16(pf, vf, oac[dt], 0, 0, 0);
            }
        }
        __builtin_amdgcn_s_setprio(0);

        // end barrier: drains my staging (vmcnt(0)) -> Ks/Vs[cur^1] sealed
        // for the next iteration; also ends this iter's Ks/Pl read window.
        __syncthreads();
        cur ^= 1;
    }
#undef KSTAGE
#undef VSTAGE

    const float li = 1.0f / lrun;
#pragma unroll
    for (int r = 0; r < 4; ++r) {
        const float ir = __shfl(li, quad * 4 + r);
        const int qrow = qt * 64 + w * 16 + quad * 4 + r;
        __hip_bfloat16* orow = ao + ((size_t)b * NN + qrow) * N_QKV + h * DH;
#pragma unroll
        for (int dt = 0; dt < 4; ++dt)
            orow[l15 + 16 * dt] = __float2bfloat16(oac[dt][r] * ir);
    }
}

// ---------------------------------------------------------------------------
extern "C" void kernel_launch(void* const* d_in, const int* in_sizes, int n_in,
                              void* d_out, int out_size, void* d_ws, size_t ws_size,
                              hipStream_t stream) {
    const float* x      = (const float*)d_in[0];
    const float* sct    = (const float*)d_in[1];
    const float* W_qkv  = (const float*)d_in[2];
    const float* W_proj = (const float*)d_in[3];
    const float* b_proj = (const float*)d_in[4];
    float* out = (float*)d_out;

    // ws layout (bytes), total 125.0 MB (same as R1-proven):
    //   [0, 30.08M):    xt bf16 [19584][768]  -> later reused as VT bf16
    //                   [192*64][1224] (identical size: 30,081,024 B)
    //   [30.08M, 120.3M): qkv bf16 [19584][2304]; attention output is written
    //                     into the (dead after transpose) V columns [1536..2304)
    //   then WT_qkv bf16 [2304][768], WT_proj bf16 [768][768]
    char* p = (char*)d_ws;
    __hip_bfloat16* xt      = (__hip_bfloat16*)p;
    __hip_bfloat16* vtg     = (__hip_bfloat16*)p;            // aliases xt (dead)
    __hip_bfloat16* qkv     = (__hip_bfloat16*)(p + (size_t)MPAD * CC * 2);
    __hip_bfloat16* WTqkv   = (__hip_bfloat16*)(p + (size_t)MPAD * CC * 2 + (size_t)MPAD * N_QKV * 2);
    __hip_bfloat16* WTproj  = WTqkv + (size_t)N_QKV * CC;
    __hip_bfloat16* ao      = qkv + 2 * CC;                  // attn out, stride N_QKV

    cast_xt_kernel<<<MPAD * 96 / 256, 256, 0, stream>>>(x, sct, xt);
    cast_wt_kernel<<<N_QKV * 96 / 256, 256, 0, stream>>>(W_qkv, WTqkv, N_QKV);
    cast_wt_kernel<<<CC * 96 / 256, 256, 0, stream>>>(W_proj, WTproj, CC);

    mfma_gemm_bt<true, true><<<dim3(N_QKV / 128, MPAD / 128), 256, 0, stream>>>(
        xt, WTqkv, qkv, nullptr, CC, CC, N_QKV);
    transpose_v_kernel<<<dim3((N1 + 63) / 64, HH, BB), 256, 0, stream>>>(qkv, vtg);
    attn_mfma_kernel<<<dim3(NN / 64, HH, BB), 256, 0, stream>>>(qkv, vtg, ao);
    mfma_gemm_bt<false, false><<<dim3(CC / 128, M_PROJ / 128), 256, 0, stream>>>(
        ao, WTproj, out, b_proj, N_QKV, CC, CC);
}